// Round 18
// baseline (220.338 us; speedup 1.0000x reference)
//
#include <hip/hip_runtime.h>

#define NROWS 65536
#define KCODES 1024
#define DDIM 256

// output offsets in floats (concat of reference return tuple)
#define Q_OFF    0
#define LOSS_OFF 16777216
#define PERP_OFF 16777217
#define IND_OFF  16777218
#define DIST_OFF 16842754

#define MARGIN  1.5e-3f
#define PRUNE   1.5e-3f
#define MAXCAND 16
#define RG_BLOCKS (NROWS / 16)   // 4096 blocks, 16 rows each

typedef unsigned long long u64;
typedef unsigned int u32;
typedef unsigned short u16;
typedef __attribute__((ext_vector_type(8))) short bf16x8;
typedef __attribute__((ext_vector_type(4))) float f32x4;

// RNE float->bf16 bits (no NaN handling; inputs are tame)
__device__ inline u32 f2bf_bits(float f) {
    u32 u = __float_as_uint(f);
    return (u + 0x7fffu + ((u >> 16) & 1u)) >> 16;
}

// ---------------- squared norms (unchanged order -> stable rs/es bits) --------
__global__ __launch_bounds__(256) void sqnorm_kernel(
    const float* __restrict__ lat, const float* __restrict__ emb,
    float* __restrict__ row_sq, float* __restrict__ emb_sq) {
    int gwave = (blockIdx.x * 256 + threadIdx.x) >> 6;
    int lane = threadIdx.x & 63;
    if (gwave >= NROWS + KCODES) return;
    const float* src = (gwave < NROWS) ? lat + (size_t)gwave * DDIM
                                       : emb + (size_t)(gwave - NROWS) * DDIM;
    float4 v = *reinterpret_cast<const float4*>(src + lane * 4);
    float s = v.x * v.x + v.y * v.y + v.z * v.z + v.w * v.w;
#pragma unroll
    for (int m = 32; m >= 1; m >>= 1) s += __shfl_xor(s, m, 64);
    if (lane == 0) {
        if (gwave < NROWS) row_sq[gwave] = s;
        else emb_sq[gwave - NROWS] = s;
    }
}

// -------- fp32 -> bf16 (hi only), TILED + CHUNK-SWIZZLED, BK=32 layout --------
// Apre[tile][ks 0..7][r 0..127][chunk 0..3]; chunk = 16B = 8 bf16 covering
// k = c*8..c*8+7 of this 32-wide K-step; logical chunk c stored at c ^ (r&3).
// Also zero-inits cand_cnt and hist (fused init).
__global__ __launch_bounds__(256) void convert_kernel(
    const float* __restrict__ lat, const float* __restrict__ emb,
    u16* __restrict__ Apre, u16* __restrict__ Bpre,
    u32* __restrict__ cand_cnt, u32* __restrict__ hist) {
    const int NA_IT = NROWS * 32;   // (rowgroup, ks, c) items
    const int NB_IT = KCODES * 32;
    int g = blockIdx.x * 256 + threadIdx.x;
    if (g < NROWS) cand_cnt[g] = 0u;
    if (g < KCODES) hist[g] = 0u;
    if (g >= NA_IT + NB_IT) return;
    const float* src;
    uint4* dst;
    int it;
    if (g < NA_IT) { src = lat; dst = (uint4*)Apre; it = g; }
    else           { src = emb; dst = (uint4*)Bpre; it = g - NA_IT; }
    int c = it & 3, ks = (it >> 2) & 7, rg = it >> 5;
    const float* s = src + (size_t)rg * DDIM + ks * 32 + c * 8;
    float4 v0 = *reinterpret_cast<const float4*>(s);
    float4 v1 = *reinterpret_cast<const float4*>(s + 4);
    u32 h0 = f2bf_bits(v0.x), h1 = f2bf_bits(v0.y), h2 = f2bf_bits(v0.z), h3 = f2bf_bits(v0.w);
    u32 h4 = f2bf_bits(v1.x), h5 = f2bf_bits(v1.y), h6 = f2bf_bits(v1.z), h7 = f2bf_bits(v1.w);
    uint4 hq = make_uint4(h0 | (h1 << 16), h2 | (h3 << 16), h4 | (h5 << 16), h6 | (h7 << 16));
    int r = rg & 127, tile = rg >> 7;
    dst[((size_t)(tile * 8 + ks) * 128 + r) * 4 + (c ^ (r & 3))] = hq;
}

// ---- dist: 32-row panel. Block = 32 rows x 1024 cols, barrier-free K-loop.
// Each B fragment feeds 2 MFMAs (2 row-frags) -> half the L2 B-read traffic
// vs 16-row panels. Epilogue: 4 passes of 8 rows, contiguous 4KB row stores.
// MFMA chain per output ascending ks, identical operands -> dv bits identical.
__global__ __launch_bounds__(256, 2) void dist_row_kernel(
    const u16* __restrict__ Apre, const u16* __restrict__ Bpre,
    const float* __restrict__ row_sq, const float* __restrict__ emb_sq,
    float* __restrict__ dist, u32* __restrict__ cand_cnt,
    u16* __restrict__ cand, float* __restrict__ cand_dv) {
    __shared__ __align__(16) float tr[8 * 1032];       // 33 KB transpose buffer
    __shared__ float rowmin_lds[4][32];
    const int tid = threadIdx.x;
    const int lane = tid & 63, w = tid >> 6;
    const int li = lane & 15, lg = lane >> 4;
    const int row0 = blockIdx.x * 32;
    const int tA = row0 >> 7;
    const int rloc = (row0 & 127) + li;                // A row frag0 within tile
    const int wcol0 = w * 256;

    f32x4 acc0[16], acc1[16];
#pragma unroll
    for (int j = 0; j < 16; ++j) { acc0[j] = (f32x4)0.0f; acc1[j] = (f32x4)0.0f; }

    const char* Abase = (const char*)Apre + (size_t)tA * 65536;
    const char* Bbase = (const char*)Bpre;

#pragma unroll
    for (int ks = 0; ks < 8; ++ks) {
        bf16x8 af0 = *reinterpret_cast<const bf16x8*>(
            Abase + ((size_t)(ks * 128 + rloc)) * 64 + ((lg ^ (rloc & 3)) << 4));
        int rloc1 = rloc + 16;
        bf16x8 af1 = *reinterpret_cast<const bf16x8*>(
            Abase + ((size_t)(ks * 128 + rloc1)) * 64 + ((lg ^ (rloc1 & 3)) << 4));
#pragma unroll
        for (int j = 0; j < 16; ++j) {
            int cc = wcol0 + j * 16 + li;
            int tb = cc >> 7, cloc = cc & 127;
            bf16x8 bf = *reinterpret_cast<const bf16x8*>(
                Bbase + ((size_t)(tb * 8 + ks) * 128 + cloc) * 64 +
                ((lg ^ (cloc & 3)) << 4));
            acc0[j] = __builtin_amdgcn_mfma_f32_16x16x32_bf16(af0, bf, acc0[j], 0, 0, 0);
            acc1[j] = __builtin_amdgcn_mfma_f32_16x16x32_bf16(af1, bf, acc1[j], 0, 0, 0);
        }
    }

    // ---------------- epilogue ------------------------------------------------
    // C/D layout per frag: row = lg*4 + rg (+ fi*16), col = j*16 + li
    float rs0[4], rs1[4], es16[16];
#pragma unroll
    for (int rg = 0; rg < 4; ++rg) {
        rs0[rg] = row_sq[row0 + lg * 4 + rg];
        rs1[rg] = row_sq[row0 + 16 + lg * 4 + rg];
    }
#pragma unroll
    for (int j = 0; j < 16; ++j) es16[j] = emb_sq[wcol0 + j * 16 + li];

    float rmin0[4] = {3.4e38f, 3.4e38f, 3.4e38f, 3.4e38f};
    float rmin1[4] = {3.4e38f, 3.4e38f, 3.4e38f, 3.4e38f};
#pragma unroll
    for (int j = 0; j < 16; ++j)
#pragma unroll
        for (int rg = 0; rg < 4; ++rg) {
            rmin0[rg] = fminf(rmin0[rg], (rs0[rg] + es16[j]) - 2.0f * acc0[j][rg]);
            rmin1[rg] = fminf(rmin1[rg], (rs1[rg] + es16[j]) - 2.0f * acc1[j][rg]);
        }
#pragma unroll
    for (int m = 8; m >= 1; m >>= 1)
#pragma unroll
        for (int rg = 0; rg < 4; ++rg) {
            rmin0[rg] = fminf(rmin0[rg], __shfl_xor(rmin0[rg], m, 64));
            rmin1[rg] = fminf(rmin1[rg], __shfl_xor(rmin1[rg], m, 64));
        }
    if (li == 0) {
#pragma unroll
        for (int rg = 0; rg < 4; ++rg) {
            rowmin_lds[w][lg * 4 + rg] = rmin0[rg];
            rowmin_lds[w][16 + lg * 4 + rg] = rmin1[rg];
        }
    }
    __syncthreads();
    float rowm0[4], rowm1[4];
#pragma unroll
    for (int rg = 0; rg < 4; ++rg) {
        int rl = lg * 4 + rg;
        rowm0[rg] = fminf(fminf(rowmin_lds[0][rl], rowmin_lds[1][rl]),
                          fminf(rowmin_lds[2][rl], rowmin_lds[3][rl])) + MARGIN;
        rowm1[rg] = fminf(fminf(rowmin_lds[0][16 + rl], rowmin_lds[1][16 + rl]),
                          fminf(rowmin_lds[2][16 + rl], rowmin_lds[3][16 + rl])) + MARGIN;
    }

    // candidate recording (true full-row min threshold; superset property holds)
#pragma unroll
    for (int j = 0; j < 16; ++j)
#pragma unroll
        for (int rg = 0; rg < 4; ++rg) {
            float dv0 = (rs0[rg] + es16[j]) - 2.0f * acc0[j][rg];
            if (dv0 <= rowm0[rg]) {
                int grow = row0 + lg * 4 + rg;
                u32 slot = atomicAdd(&cand_cnt[grow], 1u);
                if (slot < MAXCAND) {
                    cand[(size_t)grow * MAXCAND + slot] = (u16)(wcol0 + j * 16 + li);
                    cand_dv[(size_t)grow * MAXCAND + slot] = dv0;
                }
            }
            float dv1 = (rs1[rg] + es16[j]) - 2.0f * acc1[j][rg];
            if (dv1 <= rowm1[rg]) {
                int grow = row0 + 16 + lg * 4 + rg;
                u32 slot = atomicAdd(&cand_cnt[grow], 1u);
                if (slot < MAXCAND) {
                    cand[(size_t)grow * MAXCAND + slot] = (u16)(wcol0 + j * 16 + li);
                    cand_dv[(size_t)grow * MAXCAND + slot] = dv1;
                }
            }
        }

    // dist write: 4 passes of 8 rows; owning lanes fill tr, then each wave
    // streams 2 full 4KB rows contiguously (fill-like writes).
#pragma unroll
    for (int p = 0; p < 4; ++p) {
        __syncthreads();
#pragma unroll
        for (int fi = 0; fi < 2; ++fi)
#pragma unroll
            for (int rg = 0; rg < 4; ++rg) {
                int rl = fi * 16 + lg * 4 + rg;       // 0..31
                if ((rl >> 3) == p) {
#pragma unroll
                    for (int j = 0; j < 16; ++j) {
                        float dv = fi ? (rs1[rg] + es16[j]) - 2.0f * acc1[j][rg]
                                      : (rs0[rg] + es16[j]) - 2.0f * acc0[j][rg];
                        tr[(rl & 7) * 1032 + wcol0 + j * 16 + li] = dv;
                    }
                }
            }
        __syncthreads();
#pragma unroll
        for (int rr = 0; rr < 2; ++rr) {
            int r = w * 2 + rr;            // 0..7 within pass
#pragma unroll
            for (int it = 0; it < 4; ++it) {
                float4 v = *reinterpret_cast<const float4*>(
                    &tr[r * 1032 + it * 256 + lane * 4]);
                *reinterpret_cast<float4*>(
                    dist + (size_t)(row0 + p * 8 + r) * KCODES + it * 256 + lane * 4) = v;
            }
        }
    }
}

// ------- refine: bit-exact fp32 serial-FMA compare; 4 rows/wave, 8-deep MLP ---
// Prunes candidates via approx-dv (rescore only within PRUNE of approx-min);
// pruned lanes dup the first survivor (loads coalesce). Overflow -> full rescan.
__global__ __launch_bounds__(256) void refine_gather_kernel(
    const float* __restrict__ lat, const float* __restrict__ emb,
    const float* __restrict__ row_sq, const float* __restrict__ emb_sq,
    const u32* __restrict__ cand_cnt, const u16* __restrict__ cand,
    const float* __restrict__ cand_dv,
    float* __restrict__ qout, float* __restrict__ indout,
    u32* __restrict__ hist, float* __restrict__ loss_part) {
    __shared__ __align__(16) float xs[4][4][260];  // [wave][rowInWave][256+pad]
    __shared__ int bestc_l[16];
    __shared__ float lred[4];
    const int w = threadIdx.x >> 6, lane = threadIdx.x & 63;
    const int rw = lane >> 4, slot = lane & 15;
    const int row0 = blockIdx.x * 16;

#pragma unroll
    for (int rr = 0; rr < 4; ++rr) {
        int row = row0 + w * 4 + rr;
        float4 xv = *reinterpret_cast<const float4*>(lat + (size_t)row * DDIM + lane * 4);
        *reinterpret_cast<float4*>(&xs[w][rr][lane * 4]) = xv;
    }
    __syncthreads();

    const int row = row0 + w * 4 + rw;
    int cntraw = (int)cand_cnt[row];
    int cnt = (cntraw > MAXCAND) ? MAXCAND : cntraw;
    int sl = (slot < cnt) ? slot : 0;   // cnt >= 1 always (row-min is recorded)
    int c = cand[(size_t)row * MAXCAND + sl];
    float cd = cand_dv[(size_t)row * MAXCAND + sl];

    // prune: approx-min over the 16 slots; rescore only within PRUNE of it
    float cm = cd;
#pragma unroll
    for (int m = 8; m >= 1; m >>= 1) cm = fminf(cm, __shfl_xor(cm, m, 64));
    bool keep = cd <= cm + PRUNE;
    u64 bal = __ballot(keep);
    u32 mask16 = (u32)(bal >> (rw * 16)) & 0xFFFFu;
    int s0 = __ffs(mask16) - 1;        // >=0: the approx-min itself survives
    if (!keep) {
        sl = s0;
        c = cand[(size_t)row * MAXCAND + s0];
    }

    const float* erow = emb + (size_t)c * DDIM;
    float4 e0 = *reinterpret_cast<const float4*>(erow + 0);
    float4 e1 = *reinterpret_cast<const float4*>(erow + 4);
    float4 e2 = *reinterpret_cast<const float4*>(erow + 8);
    float4 e3 = *reinterpret_cast<const float4*>(erow + 12);
    float4 e4 = *reinterpret_cast<const float4*>(erow + 16);
    float4 e5 = *reinterpret_cast<const float4*>(erow + 20);
    float4 e6 = *reinterpret_cast<const float4*>(erow + 24);
    float4 e7 = *reinterpret_cast<const float4*>(erow + 28);
    float acc = 0.0f;
#define STEP(PF, K) { \
        float4 xq = *reinterpret_cast<const float4*>(&xs[w][rw][(K) * 4]); \
        acc = __builtin_fmaf(xq.x, PF.x, acc); \
        acc = __builtin_fmaf(xq.y, PF.y, acc); \
        acc = __builtin_fmaf(xq.z, PF.z, acc); \
        acc = __builtin_fmaf(xq.w, PF.w, acc); \
        if ((K) + 8 < 64) PF = *reinterpret_cast<const float4*>(erow + ((K) + 8) * 4); }
#define GROUP(G) STEP(e0, (G)*8+0) STEP(e1, (G)*8+1) STEP(e2, (G)*8+2) STEP(e3, (G)*8+3) \
                 STEP(e4, (G)*8+4) STEP(e5, (G)*8+5) STEP(e6, (G)*8+6) STEP(e7, (G)*8+7)
    GROUP(0) GROUP(1) GROUP(2) GROUP(3) GROUP(4) GROUP(5) GROUP(6) GROUP(7)
#undef GROUP
#undef STEP
    float t = row_sq[row] + emb_sq[c];
    float dv = __builtin_fmaf(-2.0f, acc, t);   // == t - 2*acc exactly (x2 exact)

    // lexicographic (dv, index) min over the 16 slots of this row
#pragma unroll
    for (int m = 8; m >= 1; m >>= 1) {
        float od = __shfl_xor(dv, m, 64);
        int oc = __shfl_xor(c, m, 64);
        if (od < dv || (od == dv && oc < c)) { dv = od; c = oc; }
    }

    // rare: candidate overflow -> full rescan of this row (all 64 lanes)
    u64 ovm = __ballot(slot == 0 && cntraw > MAXCAND);
    while (ovm) {
        int l = __ffsll((long long)ovm) - 1;
        ovm &= ovm - 1;
        int ow = l >> 4;                  // rw of the overflowing row
        int orow = row0 + w * 4 + ow;
        float tbase = row_sq[orow];
        float bdv = 3.4e38f;
        int bc = KCODES;
        for (int j = 0; j < 16; ++j) {
            int cc = lane + j * 64;
            const float* er = emb + (size_t)cc * DDIM;
            float a2 = 0.0f;
            for (int k4 = 0; k4 < 64; ++k4) {
                float4 ev = *reinterpret_cast<const float4*>(er + k4 * 4);
                float4 xq = *reinterpret_cast<const float4*>(&xs[w][ow][k4 * 4]);
                a2 = __builtin_fmaf(xq.x, ev.x, a2);
                a2 = __builtin_fmaf(xq.y, ev.y, a2);
                a2 = __builtin_fmaf(xq.z, ev.z, a2);
                a2 = __builtin_fmaf(xq.w, ev.w, a2);
            }
            float dv2 = __builtin_fmaf(-2.0f, a2, tbase + emb_sq[cc]);
            if (dv2 < bdv || (dv2 == bdv && cc < bc)) { bdv = dv2; bc = cc; }
        }
#pragma unroll
        for (int m = 32; m >= 1; m >>= 1) {
            float od = __shfl_xor(bdv, m, 64);
            int oc = __shfl_xor(bc, m, 64);
            if (od < bdv || (od == bdv && oc < bc)) { bdv = od; bc = oc; }
        }
        if (rw == ow) { dv = bdv; c = bc; }
    }

    if (slot == 0) {
        bestc_l[w * 4 + rw] = c;
        indout[row] = (float)c;
        atomicAdd(&hist[c], 1u);
    }
    __syncthreads();

    // gather phase: pass p -> wave w handles local row p*4+w == xs[p][w]
    float ssum = 0.0f;
#pragma unroll
    for (int p = 0; p < 4; ++p) {
        int rl = p * 4 + w;
        int grow = row0 + rl;
        int bc = bestc_l[rl];
        float4 xv = *reinterpret_cast<const float4*>(&xs[p][w][lane * 4]);
        float4 ev = *reinterpret_cast<const float4*>(emb + (size_t)bc * DDIM + lane * 4);
        float dx = ev.x - xv.x, dy = ev.y - xv.y, dz = ev.z - xv.z, dw = ev.w - xv.w;
        float4 q = make_float4(xv.x + dx, xv.y + dy, xv.z + dz, xv.w + dw);
        *reinterpret_cast<float4*>(qout + (size_t)grow * DDIM + lane * 4) = q;
        float s = dx * dx + dy * dy + dz * dz + dw * dw;
#pragma unroll
        for (int m = 32; m >= 1; m >>= 1) s += __shfl_xor(s, m, 64);
        ssum += s;
    }
    if (lane == 0) lred[w] = ssum;
    __syncthreads();
    if (threadIdx.x == 0)
        loss_part[blockIdx.x] = (lred[0] + lred[1]) + (lred[2] + lred[3]);
}

// ---------------- scalars: vq_loss (reduce partials), perplexity ---------------
__global__ __launch_bounds__(1024) void scalar_kernel(
    const u32* __restrict__ hist, const float* __restrict__ loss_part,
    float* __restrict__ out_loss, float* __restrict__ out_perp) {
    __shared__ double lred[16];
    __shared__ float ered[16];
    int t = threadIdx.x;
    double ls = 0.0;
#pragma unroll
    for (int i = 0; i < RG_BLOCKS / 1024; ++i)
        ls += (double)loss_part[t + i * 1024];
    float p = (float)hist[t] / 65536.0f;
    float es = p * logf(p + 1e-10f);
#pragma unroll
    for (int m = 32; m >= 1; m >>= 1) {
        ls += __shfl_xor(ls, m, 64);
        es += __shfl_xor(es, m, 64);
    }
    if ((t & 63) == 0) { lred[t >> 6] = ls; ered[t >> 6] = es; }
    __syncthreads();
    if (t < 64) {
        double lv = (t < 16) ? lred[t] : 0.0;
        float ev = (t < 16) ? ered[t] : 0.0f;
#pragma unroll
        for (int m = 32; m >= 1; m >>= 1) {
            lv += __shfl_xor(lv, m, 64);
            ev += __shfl_xor(ev, m, 64);
        }
        if (t == 0) {
            *out_perp = expf(-ev);
            double ml = lv / (double)((size_t)NROWS * DDIM);
            *out_loss = (float)(ml * 0.25 + ml);  // beta*commit + delta*embed (equal)
        }
    }
}

extern "C" void kernel_launch(void* const* d_in, const int* in_sizes, int n_in,
                              void* d_out, int out_size, void* d_ws, size_t ws_size,
                              hipStream_t stream) {
    const float* lat = (const float*)d_in[0];
    const float* emb = (const float*)d_in[1];
    float* out = (float*)d_out;
    char* ws = (char*)d_ws;

    u32* cand_cnt = (u32*)ws;                          // 262144 B
    u16* cand = (u16*)(ws + 262144);                   // 2097152 B
    float* cand_dv = (float*)(ws + 2359296);           // 4194304 B
    float* row_sq = (float*)(ws + 6553600);            // 262144 B
    float* emb_sq = (float*)(ws + 6815744);            // 4096 B
    u32* hist = (u32*)(ws + 6819840);                  // 4096 B
    float* loss_part = (float*)(ws + 6823936);         // 16384 B
    u16* Apre = (u16*)(ws + 6840320);                  // 33554432 B
    u16* Bpre = (u16*)(ws + 40394752);                 // 524288 B

    sqnorm_kernel<<<(NROWS + KCODES) / 4, 256, 0, stream>>>(lat, emb, row_sq, emb_sq);
    convert_kernel<<<(NROWS * 32 + KCODES * 32) / 256, 256, 0, stream>>>(
        lat, emb, Apre, Bpre, cand_cnt, hist);
    dist_row_kernel<<<2048, 256, 0, stream>>>(Apre, Bpre, row_sq, emb_sq,
                                              out + DIST_OFF, cand_cnt, cand, cand_dv);
    refine_gather_kernel<<<RG_BLOCKS, 256, 0, stream>>>(lat, emb, row_sq, emb_sq,
                                                        cand_cnt, cand, cand_dv,
                                                        out + Q_OFF, out + IND_OFF,
                                                        hist, loss_part);
    scalar_kernel<<<1, 1024, 0, stream>>>(hist, loss_part,
                                          out + LOSS_OFF, out + PERP_OFF);
}

// Round 19
// 196.956 us; speedup vs baseline: 1.1187x; 1.1187x over previous
//
#include <hip/hip_runtime.h>

#define NROWS 65536
#define KCODES 1024
#define DDIM 256

// output offsets in floats (concat of reference return tuple)
#define Q_OFF    0
#define LOSS_OFF 16777216
#define PERP_OFF 16777217
#define IND_OFF  16777218
#define DIST_OFF 16842754

#define MARGIN  1.5e-3f
#define PRUNE   1.5e-3f
#define MAXCAND 16
#define RG_BLOCKS (NROWS / 16)   // 4096 blocks, 16 rows each

typedef unsigned long long u64;
typedef unsigned int u32;
typedef unsigned short u16;
typedef __attribute__((ext_vector_type(8))) short bf16x8;
typedef __attribute__((ext_vector_type(4))) float f32x4;

// RNE float->bf16 bits (no NaN handling; inputs are tame)
__device__ inline u32 f2bf_bits(float f) {
    u32 u = __float_as_uint(f);
    return (u + 0x7fffu + ((u >> 16) & 1u)) >> 16;
}

// ---------------- squared norms (unchanged order -> stable rs/es bits) --------
__global__ __launch_bounds__(256) void sqnorm_kernel(
    const float* __restrict__ lat, const float* __restrict__ emb,
    float* __restrict__ row_sq, float* __restrict__ emb_sq) {
    int gwave = (blockIdx.x * 256 + threadIdx.x) >> 6;
    int lane = threadIdx.x & 63;
    if (gwave >= NROWS + KCODES) return;
    const float* src = (gwave < NROWS) ? lat + (size_t)gwave * DDIM
                                       : emb + (size_t)(gwave - NROWS) * DDIM;
    float4 v = *reinterpret_cast<const float4*>(src + lane * 4);
    float s = v.x * v.x + v.y * v.y + v.z * v.z + v.w * v.w;
#pragma unroll
    for (int m = 32; m >= 1; m >>= 1) s += __shfl_xor(s, m, 64);
    if (lane == 0) {
        if (gwave < NROWS) row_sq[gwave] = s;
        else emb_sq[gwave - NROWS] = s;
    }
}

// -------- fp32 -> bf16 (hi only), TILED + CHUNK-SWIZZLED, BK=32 layout --------
// Apre[tile][ks 0..7][r 0..127][chunk 0..3]; chunk = 16B = 8 bf16 covering
// k = c*8..c*8+7 of this 32-wide K-step; logical chunk c stored at c ^ (r&3).
// Also zero-inits cand_cnt and hist (fused init).
__global__ __launch_bounds__(256) void convert_kernel(
    const float* __restrict__ lat, const float* __restrict__ emb,
    u16* __restrict__ Apre, u16* __restrict__ Bpre,
    u32* __restrict__ cand_cnt, u32* __restrict__ hist) {
    const int NA_IT = NROWS * 32;   // (rowgroup, ks, c) items
    const int NB_IT = KCODES * 32;
    int g = blockIdx.x * 256 + threadIdx.x;
    if (g < NROWS) cand_cnt[g] = 0u;
    if (g < KCODES) hist[g] = 0u;
    if (g >= NA_IT + NB_IT) return;
    const float* src;
    uint4* dst;
    int it;
    if (g < NA_IT) { src = lat; dst = (uint4*)Apre; it = g; }
    else           { src = emb; dst = (uint4*)Bpre; it = g - NA_IT; }
    int c = it & 3, ks = (it >> 2) & 7, rg = it >> 5;
    const float* s = src + (size_t)rg * DDIM + ks * 32 + c * 8;
    float4 v0 = *reinterpret_cast<const float4*>(s);
    float4 v1 = *reinterpret_cast<const float4*>(s + 4);
    u32 h0 = f2bf_bits(v0.x), h1 = f2bf_bits(v0.y), h2 = f2bf_bits(v0.z), h3 = f2bf_bits(v0.w);
    u32 h4 = f2bf_bits(v1.x), h5 = f2bf_bits(v1.y), h6 = f2bf_bits(v1.z), h7 = f2bf_bits(v1.w);
    uint4 hq = make_uint4(h0 | (h1 << 16), h2 | (h3 << 16), h4 | (h5 << 16), h6 | (h7 << 16));
    int r = rg & 127, tile = rg >> 7;
    dst[((size_t)(tile * 8 + ks) * 128 + r) * 4 + (c ^ (r & 3))] = hq;
}

// ---- dist: row-panel kernel (R17 optimum). Block = 16 rows x 1024 cols,
// barrier-free K-loop. A-frags global->VGPR; B streams from L2-resident Bpre.
// Epilogue: full-row LDS transpose -> each wave stores contiguous 4KB rows.
// MFMA chain per output ascending ks, identical operands -> dv bits identical.
__global__ __launch_bounds__(256, 3) void dist_row_kernel(
    const u16* __restrict__ Apre, const u16* __restrict__ Bpre,
    const float* __restrict__ row_sq, const float* __restrict__ emb_sq,
    float* __restrict__ dist, u32* __restrict__ cand_cnt,
    u16* __restrict__ cand, float* __restrict__ cand_dv) {
    __shared__ __align__(16) float tr[8 * 1032];       // 33 KB transpose buffer
    __shared__ float rowmin_lds[4][16];
    const int tid = threadIdx.x;
    const int lane = tid & 63, w = tid >> 6;
    const int li = lane & 15, lg = lane >> 4;
    const int row0 = blockIdx.x * 16;
    const int tA = row0 >> 7;
    const int rloc = (row0 & 127) + li;                // A row within tile
    const int wcol0 = w * 256;

    f32x4 acc[16];
#pragma unroll
    for (int nf = 0; nf < 16; ++nf) acc[nf] = (f32x4)0.0f;

    const char* Abase = (const char*)Apre + (size_t)tA * 65536;
    const char* Bbase = (const char*)Bpre;

#pragma unroll
    for (int ks = 0; ks < 8; ++ks) {
        bf16x8 af = *reinterpret_cast<const bf16x8*>(
            Abase + ((size_t)(ks * 128 + rloc)) * 64 + ((lg ^ (rloc & 3)) << 4));
#pragma unroll
        for (int g = 0; g < 2; ++g) {
            bf16x8 bf[8];
#pragma unroll
            for (int j = 0; j < 8; ++j) {
                int cc = wcol0 + (g * 8 + j) * 16 + li;
                int tb = cc >> 7, cloc = cc & 127;
                bf[j] = *reinterpret_cast<const bf16x8*>(
                    Bbase + ((size_t)(tb * 8 + ks) * 128 + cloc) * 64 +
                    ((lg ^ (cloc & 3)) << 4));
            }
#pragma unroll
            for (int j = 0; j < 8; ++j)
                acc[g * 8 + j] = __builtin_amdgcn_mfma_f32_16x16x32_bf16(
                    af, bf[j], acc[g * 8 + j], 0, 0, 0);
        }
    }

    // ---------------- epilogue ------------------------------------------------
    // C/D layout per frag: row = lg*4 + rg, col = nf*16 + li (wave base wcol0)
    float rs_r[4], es16[16];
#pragma unroll
    for (int rg = 0; rg < 4; ++rg) rs_r[rg] = row_sq[row0 + lg * 4 + rg];
#pragma unroll
    for (int nf = 0; nf < 16; ++nf) es16[nf] = emb_sq[wcol0 + nf * 16 + li];

    float rmin[4] = {3.4e38f, 3.4e38f, 3.4e38f, 3.4e38f};
#pragma unroll
    for (int nf = 0; nf < 16; ++nf)
#pragma unroll
        for (int rg = 0; rg < 4; ++rg) {
            float dv = (rs_r[rg] + es16[nf]) - 2.0f * acc[nf][rg];
            rmin[rg] = fminf(rmin[rg], dv);
        }
#pragma unroll
    for (int m = 8; m >= 1; m >>= 1)
#pragma unroll
        for (int rg = 0; rg < 4; ++rg)
            rmin[rg] = fminf(rmin[rg], __shfl_xor(rmin[rg], m, 64));
    if (li == 0) {
#pragma unroll
        for (int rg = 0; rg < 4; ++rg) rowmin_lds[w][lg * 4 + rg] = rmin[rg];
    }
    __syncthreads();
    float rowm[4];
#pragma unroll
    for (int rg = 0; rg < 4; ++rg) {
        float a = fminf(rowmin_lds[0][lg * 4 + rg], rowmin_lds[1][lg * 4 + rg]);
        float b = fminf(rowmin_lds[2][lg * 4 + rg], rowmin_lds[3][lg * 4 + rg]);
        rowm[rg] = fminf(a, b) + MARGIN;
    }

    // candidate recording (true full-row min threshold; superset property holds)
#pragma unroll
    for (int nf = 0; nf < 16; ++nf)
#pragma unroll
        for (int rg = 0; rg < 4; ++rg) {
            float dv = (rs_r[rg] + es16[nf]) - 2.0f * acc[nf][rg];
            if (dv <= rowm[rg]) {
                int grow = row0 + lg * 4 + rg;
                u32 slot = atomicAdd(&cand_cnt[grow], 1u);
                if (slot < MAXCAND) {
                    cand[(size_t)grow * MAXCAND + slot] = (u16)(wcol0 + nf * 16 + li);
                    cand_dv[(size_t)grow * MAXCAND + slot] = dv;
                }
            }
        }

    // dist write: 2 passes of 8 rows; owning lanes (lg>>1 == p) fill tr, then
    // each wave streams 2 full 4KB rows contiguously (fill-like writes).
#pragma unroll
    for (int p = 0; p < 2; ++p) {
        __syncthreads();
        if ((lg >> 1) == p) {
#pragma unroll
            for (int nf = 0; nf < 16; ++nf)
#pragma unroll
                for (int rg = 0; rg < 4; ++rg) {
                    float dv = (rs_r[rg] + es16[nf]) - 2.0f * acc[nf][rg];
                    tr[((lg & 1) * 4 + rg) * 1032 + wcol0 + nf * 16 + li] = dv;
                }
        }
        __syncthreads();
#pragma unroll
        for (int rr = 0; rr < 2; ++rr) {
            int r = w * 2 + rr;            // 0..7 within pass
#pragma unroll
            for (int it = 0; it < 4; ++it) {
                float4 v = *reinterpret_cast<const float4*>(
                    &tr[r * 1032 + it * 256 + lane * 4]);
                *reinterpret_cast<float4*>(
                    dist + (size_t)(row0 + p * 8 + r) * KCODES + it * 256 + lane * 4) = v;
            }
        }
    }
}

// ------- refine: bit-exact fp32 serial-FMA compare; 4 rows/wave, 8-deep MLP ---
// Prunes candidates via approx-dv (rescore only within PRUNE of approx-min);
// pruned lanes dup the first survivor (loads coalesce). Overflow -> full rescan.
__global__ __launch_bounds__(256) void refine_gather_kernel(
    const float* __restrict__ lat, const float* __restrict__ emb,
    const float* __restrict__ row_sq, const float* __restrict__ emb_sq,
    const u32* __restrict__ cand_cnt, const u16* __restrict__ cand,
    const float* __restrict__ cand_dv,
    float* __restrict__ qout, float* __restrict__ indout,
    u32* __restrict__ hist, float* __restrict__ loss_part) {
    __shared__ __align__(16) float xs[4][4][260];  // [wave][rowInWave][256+pad]
    __shared__ int bestc_l[16];
    __shared__ float lred[4];
    const int w = threadIdx.x >> 6, lane = threadIdx.x & 63;
    const int rw = lane >> 4, slot = lane & 15;
    const int row0 = blockIdx.x * 16;

#pragma unroll
    for (int rr = 0; rr < 4; ++rr) {
        int row = row0 + w * 4 + rr;
        float4 xv = *reinterpret_cast<const float4*>(lat + (size_t)row * DDIM + lane * 4);
        *reinterpret_cast<float4*>(&xs[w][rr][lane * 4]) = xv;
    }
    __syncthreads();

    const int row = row0 + w * 4 + rw;
    int cntraw = (int)cand_cnt[row];
    int cnt = (cntraw > MAXCAND) ? MAXCAND : cntraw;
    int sl = (slot < cnt) ? slot : 0;   // cnt >= 1 always (row-min is recorded)
    int c = cand[(size_t)row * MAXCAND + sl];
    float cd = cand_dv[(size_t)row * MAXCAND + sl];

    // prune: approx-min over the 16 slots; rescore only within PRUNE of it
    float cm = cd;
#pragma unroll
    for (int m = 8; m >= 1; m >>= 1) cm = fminf(cm, __shfl_xor(cm, m, 64));
    bool keep = cd <= cm + PRUNE;
    u64 bal = __ballot(keep);
    u32 mask16 = (u32)(bal >> (rw * 16)) & 0xFFFFu;
    int s0 = __ffs(mask16) - 1;        // >=0: the approx-min itself survives
    if (!keep) {
        sl = s0;
        c = cand[(size_t)row * MAXCAND + s0];
    }

    const float* erow = emb + (size_t)c * DDIM;
    float4 e0 = *reinterpret_cast<const float4*>(erow + 0);
    float4 e1 = *reinterpret_cast<const float4*>(erow + 4);
    float4 e2 = *reinterpret_cast<const float4*>(erow + 8);
    float4 e3 = *reinterpret_cast<const float4*>(erow + 12);
    float4 e4 = *reinterpret_cast<const float4*>(erow + 16);
    float4 e5 = *reinterpret_cast<const float4*>(erow + 20);
    float4 e6 = *reinterpret_cast<const float4*>(erow + 24);
    float4 e7 = *reinterpret_cast<const float4*>(erow + 28);
    float acc = 0.0f;
#define STEP(PF, K) { \
        float4 xq = *reinterpret_cast<const float4*>(&xs[w][rw][(K) * 4]); \
        acc = __builtin_fmaf(xq.x, PF.x, acc); \
        acc = __builtin_fmaf(xq.y, PF.y, acc); \
        acc = __builtin_fmaf(xq.z, PF.z, acc); \
        acc = __builtin_fmaf(xq.w, PF.w, acc); \
        if ((K) + 8 < 64) PF = *reinterpret_cast<const float4*>(erow + ((K) + 8) * 4); }
#define GROUP(G) STEP(e0, (G)*8+0) STEP(e1, (G)*8+1) STEP(e2, (G)*8+2) STEP(e3, (G)*8+3) \
                 STEP(e4, (G)*8+4) STEP(e5, (G)*8+5) STEP(e6, (G)*8+6) STEP(e7, (G)*8+7)
    GROUP(0) GROUP(1) GROUP(2) GROUP(3) GROUP(4) GROUP(5) GROUP(6) GROUP(7)
#undef GROUP
#undef STEP
    float t = row_sq[row] + emb_sq[c];
    float dv = __builtin_fmaf(-2.0f, acc, t);   // == t - 2*acc exactly (x2 exact)

    // lexicographic (dv, index) min over the 16 slots of this row
#pragma unroll
    for (int m = 8; m >= 1; m >>= 1) {
        float od = __shfl_xor(dv, m, 64);
        int oc = __shfl_xor(c, m, 64);
        if (od < dv || (od == dv && oc < c)) { dv = od; c = oc; }
    }

    // rare: candidate overflow -> full rescan of this row (all 64 lanes)
    u64 ovm = __ballot(slot == 0 && cntraw > MAXCAND);
    while (ovm) {
        int l = __ffsll((long long)ovm) - 1;
        ovm &= ovm - 1;
        int ow = l >> 4;                  // rw of the overflowing row
        int orow = row0 + w * 4 + ow;
        float tbase = row_sq[orow];
        float bdv = 3.4e38f;
        int bc = KCODES;
        for (int j = 0; j < 16; ++j) {
            int cc = lane + j * 64;
            const float* er = emb + (size_t)cc * DDIM;
            float a2 = 0.0f;
            for (int k4 = 0; k4 < 64; ++k4) {
                float4 ev = *reinterpret_cast<const float4*>(er + k4 * 4);
                float4 xq = *reinterpret_cast<const float4*>(&xs[w][ow][k4 * 4]);
                a2 = __builtin_fmaf(xq.x, ev.x, a2);
                a2 = __builtin_fmaf(xq.y, ev.y, a2);
                a2 = __builtin_fmaf(xq.z, ev.z, a2);
                a2 = __builtin_fmaf(xq.w, ev.w, a2);
            }
            float dv2 = __builtin_fmaf(-2.0f, a2, tbase + emb_sq[cc]);
            if (dv2 < bdv || (dv2 == bdv && cc < bc)) { bdv = dv2; bc = cc; }
        }
#pragma unroll
        for (int m = 32; m >= 1; m >>= 1) {
            float od = __shfl_xor(bdv, m, 64);
            int oc = __shfl_xor(bc, m, 64);
            if (od < bdv || (od == bdv && oc < bc)) { bdv = od; bc = oc; }
        }
        if (rw == ow) { dv = bdv; c = bc; }
    }

    if (slot == 0) {
        bestc_l[w * 4 + rw] = c;
        indout[row] = (float)c;
        atomicAdd(&hist[c], 1u);
    }
    __syncthreads();

    // gather phase: pass p -> wave w handles local row p*4+w == xs[p][w]
    float ssum = 0.0f;
#pragma unroll
    for (int p = 0; p < 4; ++p) {
        int rl = p * 4 + w;
        int grow = row0 + rl;
        int bc = bestc_l[rl];
        float4 xv = *reinterpret_cast<const float4*>(&xs[p][w][lane * 4]);
        float4 ev = *reinterpret_cast<const float4*>(emb + (size_t)bc * DDIM + lane * 4);
        float dx = ev.x - xv.x, dy = ev.y - xv.y, dz = ev.z - xv.z, dw = ev.w - xv.w;
        float4 q = make_float4(xv.x + dx, xv.y + dy, xv.z + dz, xv.w + dw);
        *reinterpret_cast<float4*>(qout + (size_t)grow * DDIM + lane * 4) = q;
        float s = dx * dx + dy * dy + dz * dz + dw * dw;
#pragma unroll
        for (int m = 32; m >= 1; m >>= 1) s += __shfl_xor(s, m, 64);
        ssum += s;
    }
    if (lane == 0) lred[w] = ssum;
    __syncthreads();
    if (threadIdx.x == 0)
        loss_part[blockIdx.x] = (lred[0] + lred[1]) + (lred[2] + lred[3]);
}

// ---------------- scalars: vq_loss (reduce partials), perplexity ---------------
__global__ __launch_bounds__(1024) void scalar_kernel(
    const u32* __restrict__ hist, const float* __restrict__ loss_part,
    float* __restrict__ out_loss, float* __restrict__ out_perp) {
    __shared__ double lred[16];
    __shared__ float ered[16];
    int t = threadIdx.x;
    double ls = 0.0;
#pragma unroll
    for (int i = 0; i < RG_BLOCKS / 1024; ++i)
        ls += (double)loss_part[t + i * 1024];
    float p = (float)hist[t] / 65536.0f;
    float es = p * logf(p + 1e-10f);
#pragma unroll
    for (int m = 32; m >= 1; m >>= 1) {
        ls += __shfl_xor(ls, m, 64);
        es += __shfl_xor(es, m, 64);
    }
    if ((t & 63) == 0) { lred[t >> 6] = ls; ered[t >> 6] = es; }
    __syncthreads();
    if (t < 64) {
        double lv = (t < 16) ? lred[t] : 0.0;
        float ev = (t < 16) ? ered[t] : 0.0f;
#pragma unroll
        for (int m = 32; m >= 1; m >>= 1) {
            lv += __shfl_xor(lv, m, 64);
            ev += __shfl_xor(ev, m, 64);
        }
        if (t == 0) {
            *out_perp = expf(-ev);
            double ml = lv / (double)((size_t)NROWS * DDIM);
            *out_loss = (float)(ml * 0.25 + ml);  // beta*commit + delta*embed (equal)
        }
    }
}

extern "C" void kernel_launch(void* const* d_in, const int* in_sizes, int n_in,
                              void* d_out, int out_size, void* d_ws, size_t ws_size,
                              hipStream_t stream) {
    const float* lat = (const float*)d_in[0];
    const float* emb = (const float*)d_in[1];
    float* out = (float*)d_out;
    char* ws = (char*)d_ws;

    u32* cand_cnt = (u32*)ws;                          // 262144 B
    u16* cand = (u16*)(ws + 262144);                   // 2097152 B
    float* cand_dv = (float*)(ws + 2359296);           // 4194304 B
    float* row_sq = (float*)(ws + 6553600);            // 262144 B
    float* emb_sq = (float*)(ws + 6815744);            // 4096 B
    u32* hist = (u32*)(ws + 6819840);                  // 4096 B
    float* loss_part = (float*)(ws + 6823936);         // 16384 B
    u16* Apre = (u16*)(ws + 6840320);                  // 33554432 B
    u16* Bpre = (u16*)(ws + 40394752);                 // 524288 B

    sqnorm_kernel<<<(NROWS + KCODES) / 4, 256, 0, stream>>>(lat, emb, row_sq, emb_sq);
    convert_kernel<<<(NROWS * 32 + KCODES * 32) / 256, 256, 0, stream>>>(
        lat, emb, Apre, Bpre, cand_cnt, hist);
    dist_row_kernel<<<4096, 256, 0, stream>>>(Apre, Bpre, row_sq, emb_sq,
                                              out + DIST_OFF, cand_cnt, cand, cand_dv);
    refine_gather_kernel<<<RG_BLOCKS, 256, 0, stream>>>(lat, emb, row_sq, emb_sq,
                                                        cand_cnt, cand, cand_dv,
                                                        out + Q_OFF, out + IND_OFF,
                                                        hist, loss_part);
    scalar_kernel<<<1, 1024, 0, stream>>>(hist, loss_part,
                                          out + LOSS_OFF, out + PERP_OFF);
}

// Round 20
// 185.594 us; speedup vs baseline: 1.1872x; 1.0612x over previous
//
#include <hip/hip_runtime.h>

#define NROWS 65536
#define KCODES 1024
#define DDIM 256

// output offsets in floats (concat of reference return tuple)
#define Q_OFF    0
#define LOSS_OFF 16777216
#define PERP_OFF 16777217
#define IND_OFF  16777218
#define DIST_OFF 16842754

#define MARGIN  1.5e-3f
#define PRUNE   1.5e-3f
#define MAXCAND 16
#define RG_BLOCKS (NROWS / 16)   // 4096 blocks, 16 rows each

typedef unsigned long long u64;
typedef unsigned int u32;
typedef unsigned short u16;
typedef __attribute__((ext_vector_type(8))) short bf16x8;
typedef __attribute__((ext_vector_type(4))) float f32x4;

// RNE float->bf16 bits (no NaN handling; inputs are tame)
__device__ inline u32 f2bf_bits(float f) {
    u32 u = __float_as_uint(f);
    return (u + 0x7fffu + ((u >> 16) & 1u)) >> 16;
}

// -------- fp32 -> bf16 (hi only), TILED + CHUNK-SWIZZLED, BK=32 layout --------
// Apre[tile][ks 0..7][r 0..127][chunk 0..3]; chunk = 16B = 8 bf16 covering
// k = c*8..c*8+7 of this 32-wide K-step; logical chunk c stored at c ^ (r&3).
// FUSED: row_sq/emb_sq computed here with a butterfly that replicates the old
// sqnorm_kernel's 64-lane tree BIT-EXACTLY (even/odd factorization: lane-space
// steps 32..2 = j-space 16..1 on sE,sO; final step m=1 = sE+sO).
// Also zero-inits cand_cnt and hist.
__global__ __launch_bounds__(256) void convert_kernel(
    const float* __restrict__ lat, const float* __restrict__ emb,
    u16* __restrict__ Apre, u16* __restrict__ Bpre,
    float* __restrict__ row_sq, float* __restrict__ emb_sq,
    u32* __restrict__ cand_cnt, u32* __restrict__ hist) {
    const int NA_IT = NROWS * 32;   // (rowgroup, ks, c) items
    const int NB_IT = KCODES * 32;
    int g = blockIdx.x * 256 + threadIdx.x;
    if (g < NROWS) cand_cnt[g] = 0u;
    if (g < KCODES) hist[g] = 0u;
    if (g >= NA_IT + NB_IT) return;
    const float* src;
    uint4* dst;
    int it;
    bool isA = (g < NA_IT);
    if (isA) { src = lat; dst = (uint4*)Apre; it = g; }
    else     { src = emb; dst = (uint4*)Bpre; it = g - NA_IT; }
    int c = it & 3, ks = (it >> 2) & 7, rg = it >> 5;
    const float* s = src + (size_t)rg * DDIM + ks * 32 + c * 8;
    float4 v0 = *reinterpret_cast<const float4*>(s);
    float4 v1 = *reinterpret_cast<const float4*>(s + 4);
    u32 h0 = f2bf_bits(v0.x), h1 = f2bf_bits(v0.y), h2 = f2bf_bits(v0.z), h3 = f2bf_bits(v0.w);
    u32 h4 = f2bf_bits(v1.x), h5 = f2bf_bits(v1.y), h6 = f2bf_bits(v1.z), h7 = f2bf_bits(v1.w);
    uint4 hq = make_uint4(h0 | (h1 << 16), h2 | (h3 << 16), h4 | (h5 << 16), h6 | (h7 << 16));
    int r = rg & 127, tile = rg >> 7;
    dst[((size_t)(tile * 8 + ks) * 128 + r) * 4 + (c ^ (r & 3))] = hq;

    // fused squared-norm (bit-exact vs old sqnorm_kernel; see header comment)
    float sE = v0.x * v0.x + v0.y * v0.y + v0.z * v0.z + v0.w * v0.w;
    float sO = v1.x * v1.x + v1.y * v1.y + v1.z * v1.z + v1.w * v1.w;
#pragma unroll
    for (int m = 16; m >= 1; m >>= 1) {
        sE += __shfl_xor(sE, m, 64);
        sO += __shfl_xor(sO, m, 64);
    }
    float snorm = sE + sO;
    if ((it & 31) == 0) {
        if (isA) row_sq[rg] = snorm;
        else emb_sq[rg] = snorm;
    }
}

// ---- dist: row-panel kernel (R17 optimum). Block = 16 rows x 1024 cols,
// barrier-free K-loop. A-frags global->VGPR; B streams from L2-resident Bpre.
// Epilogue: full-row LDS transpose -> each wave stores contiguous 4KB rows.
// MFMA chain per output ascending ks, identical operands -> dv bits identical.
__global__ __launch_bounds__(256, 3) void dist_row_kernel(
    const u16* __restrict__ Apre, const u16* __restrict__ Bpre,
    const float* __restrict__ row_sq, const float* __restrict__ emb_sq,
    float* __restrict__ dist, u32* __restrict__ cand_cnt,
    u16* __restrict__ cand, float* __restrict__ cand_dv) {
    __shared__ __align__(16) float tr[8 * 1032];       // 33 KB transpose buffer
    __shared__ float rowmin_lds[4][16];
    const int tid = threadIdx.x;
    const int lane = tid & 63, w = tid >> 6;
    const int li = lane & 15, lg = lane >> 4;
    const int row0 = blockIdx.x * 16;
    const int tA = row0 >> 7;
    const int rloc = (row0 & 127) + li;                // A row within tile
    const int wcol0 = w * 256;

    f32x4 acc[16];
#pragma unroll
    for (int nf = 0; nf < 16; ++nf) acc[nf] = (f32x4)0.0f;

    const char* Abase = (const char*)Apre + (size_t)tA * 65536;
    const char* Bbase = (const char*)Bpre;

#pragma unroll
    for (int ks = 0; ks < 8; ++ks) {
        bf16x8 af = *reinterpret_cast<const bf16x8*>(
            Abase + ((size_t)(ks * 128 + rloc)) * 64 + ((lg ^ (rloc & 3)) << 4));
#pragma unroll
        for (int g = 0; g < 2; ++g) {
            bf16x8 bf[8];
#pragma unroll
            for (int j = 0; j < 8; ++j) {
                int cc = wcol0 + (g * 8 + j) * 16 + li;
                int tb = cc >> 7, cloc = cc & 127;
                bf[j] = *reinterpret_cast<const bf16x8*>(
                    Bbase + ((size_t)(tb * 8 + ks) * 128 + cloc) * 64 +
                    ((lg ^ (cloc & 3)) << 4));
            }
#pragma unroll
            for (int j = 0; j < 8; ++j)
                acc[g * 8 + j] = __builtin_amdgcn_mfma_f32_16x16x32_bf16(
                    af, bf[j], acc[g * 8 + j], 0, 0, 0);
        }
    }

    // ---------------- epilogue ------------------------------------------------
    // C/D layout per frag: row = lg*4 + rg, col = nf*16 + li (wave base wcol0)
    float rs_r[4], es16[16];
#pragma unroll
    for (int rg = 0; rg < 4; ++rg) rs_r[rg] = row_sq[row0 + lg * 4 + rg];
#pragma unroll
    for (int nf = 0; nf < 16; ++nf) es16[nf] = emb_sq[wcol0 + nf * 16 + li];

    float rmin[4] = {3.4e38f, 3.4e38f, 3.4e38f, 3.4e38f};
#pragma unroll
    for (int nf = 0; nf < 16; ++nf)
#pragma unroll
        for (int rg = 0; rg < 4; ++rg) {
            float dv = (rs_r[rg] + es16[nf]) - 2.0f * acc[nf][rg];
            rmin[rg] = fminf(rmin[rg], dv);
        }
#pragma unroll
    for (int m = 8; m >= 1; m >>= 1)
#pragma unroll
        for (int rg = 0; rg < 4; ++rg)
            rmin[rg] = fminf(rmin[rg], __shfl_xor(rmin[rg], m, 64));
    if (li == 0) {
#pragma unroll
        for (int rg = 0; rg < 4; ++rg) rowmin_lds[w][lg * 4 + rg] = rmin[rg];
    }
    __syncthreads();
    float rowm[4];
#pragma unroll
    for (int rg = 0; rg < 4; ++rg) {
        float a = fminf(rowmin_lds[0][lg * 4 + rg], rowmin_lds[1][lg * 4 + rg]);
        float b = fminf(rowmin_lds[2][lg * 4 + rg], rowmin_lds[3][lg * 4 + rg]);
        rowm[rg] = fminf(a, b) + MARGIN;
    }

    // candidate recording (true full-row min threshold; superset property holds)
#pragma unroll
    for (int nf = 0; nf < 16; ++nf)
#pragma unroll
        for (int rg = 0; rg < 4; ++rg) {
            float dv = (rs_r[rg] + es16[nf]) - 2.0f * acc[nf][rg];
            if (dv <= rowm[rg]) {
                int grow = row0 + lg * 4 + rg;
                u32 slot = atomicAdd(&cand_cnt[grow], 1u);
                if (slot < MAXCAND) {
                    cand[(size_t)grow * MAXCAND + slot] = (u16)(wcol0 + nf * 16 + li);
                    cand_dv[(size_t)grow * MAXCAND + slot] = dv;
                }
            }
        }

    // dist write: 2 passes of 8 rows; owning lanes (lg>>1 == p) fill tr, then
    // each wave streams 2 full 4KB rows contiguously (fill-like writes).
#pragma unroll
    for (int p = 0; p < 2; ++p) {
        __syncthreads();
        if ((lg >> 1) == p) {
#pragma unroll
            for (int nf = 0; nf < 16; ++nf)
#pragma unroll
                for (int rg = 0; rg < 4; ++rg) {
                    float dv = (rs_r[rg] + es16[nf]) - 2.0f * acc[nf][rg];
                    tr[((lg & 1) * 4 + rg) * 1032 + wcol0 + nf * 16 + li] = dv;
                }
        }
        __syncthreads();
#pragma unroll
        for (int rr = 0; rr < 2; ++rr) {
            int r = w * 2 + rr;            // 0..7 within pass
#pragma unroll
            for (int it = 0; it < 4; ++it) {
                float4 v = *reinterpret_cast<const float4*>(
                    &tr[r * 1032 + it * 256 + lane * 4]);
                *reinterpret_cast<float4*>(
                    dist + (size_t)(row0 + p * 8 + r) * KCODES + it * 256 + lane * 4) = v;
            }
        }
    }
}

// ------- refine: bit-exact fp32 serial-FMA compare; 4 rows/wave, 8-deep MLP ---
// Prunes candidates via approx-dv (rescore only within PRUNE of approx-min);
// pruned lanes dup the first survivor (loads coalesce). Overflow -> full rescan.
__global__ __launch_bounds__(256) void refine_gather_kernel(
    const float* __restrict__ lat, const float* __restrict__ emb,
    const float* __restrict__ row_sq, const float* __restrict__ emb_sq,
    const u32* __restrict__ cand_cnt, const u16* __restrict__ cand,
    const float* __restrict__ cand_dv,
    float* __restrict__ qout, float* __restrict__ indout,
    u32* __restrict__ hist, float* __restrict__ loss_part) {
    __shared__ __align__(16) float xs[4][4][260];  // [wave][rowInWave][256+pad]
    __shared__ int bestc_l[16];
    __shared__ float lred[4];
    const int w = threadIdx.x >> 6, lane = threadIdx.x & 63;
    const int rw = lane >> 4, slot = lane & 15;
    const int row0 = blockIdx.x * 16;

#pragma unroll
    for (int rr = 0; rr < 4; ++rr) {
        int row = row0 + w * 4 + rr;
        float4 xv = *reinterpret_cast<const float4*>(lat + (size_t)row * DDIM + lane * 4);
        *reinterpret_cast<float4*>(&xs[w][rr][lane * 4]) = xv;
    }
    __syncthreads();

    const int row = row0 + w * 4 + rw;
    int cntraw = (int)cand_cnt[row];
    int cnt = (cntraw > MAXCAND) ? MAXCAND : cntraw;
    int sl = (slot < cnt) ? slot : 0;   // cnt >= 1 always (row-min is recorded)
    int c = cand[(size_t)row * MAXCAND + sl];
    float cd = cand_dv[(size_t)row * MAXCAND + sl];

    // prune: approx-min over the 16 slots; rescore only within PRUNE of it
    float cm = cd;
#pragma unroll
    for (int m = 8; m >= 1; m >>= 1) cm = fminf(cm, __shfl_xor(cm, m, 64));
    bool keep = cd <= cm + PRUNE;
    u64 bal = __ballot(keep);
    u32 mask16 = (u32)(bal >> (rw * 16)) & 0xFFFFu;
    int s0 = __ffs(mask16) - 1;        // >=0: the approx-min itself survives
    if (!keep) {
        sl = s0;
        c = cand[(size_t)row * MAXCAND + s0];
    }

    const float* erow = emb + (size_t)c * DDIM;
    float4 e0 = *reinterpret_cast<const float4*>(erow + 0);
    float4 e1 = *reinterpret_cast<const float4*>(erow + 4);
    float4 e2 = *reinterpret_cast<const float4*>(erow + 8);
    float4 e3 = *reinterpret_cast<const float4*>(erow + 12);
    float4 e4 = *reinterpret_cast<const float4*>(erow + 16);
    float4 e5 = *reinterpret_cast<const float4*>(erow + 20);
    float4 e6 = *reinterpret_cast<const float4*>(erow + 24);
    float4 e7 = *reinterpret_cast<const float4*>(erow + 28);
    float acc = 0.0f;
#define STEP(PF, K) { \
        float4 xq = *reinterpret_cast<const float4*>(&xs[w][rw][(K) * 4]); \
        acc = __builtin_fmaf(xq.x, PF.x, acc); \
        acc = __builtin_fmaf(xq.y, PF.y, acc); \
        acc = __builtin_fmaf(xq.z, PF.z, acc); \
        acc = __builtin_fmaf(xq.w, PF.w, acc); \
        if ((K) + 8 < 64) PF = *reinterpret_cast<const float4*>(erow + ((K) + 8) * 4); }
#define GROUP(G) STEP(e0, (G)*8+0) STEP(e1, (G)*8+1) STEP(e2, (G)*8+2) STEP(e3, (G)*8+3) \
                 STEP(e4, (G)*8+4) STEP(e5, (G)*8+5) STEP(e6, (G)*8+6) STEP(e7, (G)*8+7)
    GROUP(0) GROUP(1) GROUP(2) GROUP(3) GROUP(4) GROUP(5) GROUP(6) GROUP(7)
#undef GROUP
#undef STEP
    float t = row_sq[row] + emb_sq[c];
    float dv = __builtin_fmaf(-2.0f, acc, t);   // == t - 2*acc exactly (x2 exact)

    // lexicographic (dv, index) min over the 16 slots of this row
#pragma unroll
    for (int m = 8; m >= 1; m >>= 1) {
        float od = __shfl_xor(dv, m, 64);
        int oc = __shfl_xor(c, m, 64);
        if (od < dv || (od == dv && oc < c)) { dv = od; c = oc; }
    }

    // rare: candidate overflow -> full rescan of this row (all 64 lanes)
    u64 ovm = __ballot(slot == 0 && cntraw > MAXCAND);
    while (ovm) {
        int l = __ffsll((long long)ovm) - 1;
        ovm &= ovm - 1;
        int ow = l >> 4;                  // rw of the overflowing row
        int orow = row0 + w * 4 + ow;
        float tbase = row_sq[orow];
        float bdv = 3.4e38f;
        int bc = KCODES;
        for (int j = 0; j < 16; ++j) {
            int cc = lane + j * 64;
            const float* er = emb + (size_t)cc * DDIM;
            float a2 = 0.0f;
            for (int k4 = 0; k4 < 64; ++k4) {
                float4 ev = *reinterpret_cast<const float4*>(er + k4 * 4);
                float4 xq = *reinterpret_cast<const float4*>(&xs[w][ow][k4 * 4]);
                a2 = __builtin_fmaf(xq.x, ev.x, a2);
                a2 = __builtin_fmaf(xq.y, ev.y, a2);
                a2 = __builtin_fmaf(xq.z, ev.z, a2);
                a2 = __builtin_fmaf(xq.w, ev.w, a2);
            }
            float dv2 = __builtin_fmaf(-2.0f, a2, tbase + emb_sq[cc]);
            if (dv2 < bdv || (dv2 == bdv && cc < bc)) { bdv = dv2; bc = cc; }
        }
#pragma unroll
        for (int m = 32; m >= 1; m >>= 1) {
            float od = __shfl_xor(bdv, m, 64);
            int oc = __shfl_xor(bc, m, 64);
            if (od < bdv || (od == bdv && oc < bc)) { bdv = od; bc = oc; }
        }
        if (rw == ow) { dv = bdv; c = bc; }
    }

    if (slot == 0) {
        bestc_l[w * 4 + rw] = c;
        indout[row] = (float)c;
        atomicAdd(&hist[c], 1u);
    }
    __syncthreads();

    // gather phase: pass p -> wave w handles local row p*4+w == xs[p][w]
    float ssum = 0.0f;
#pragma unroll
    for (int p = 0; p < 4; ++p) {
        int rl = p * 4 + w;
        int grow = row0 + rl;
        int bc = bestc_l[rl];
        float4 xv = *reinterpret_cast<const float4*>(&xs[p][w][lane * 4]);
        float4 ev = *reinterpret_cast<const float4*>(emb + (size_t)bc * DDIM + lane * 4);
        float dx = ev.x - xv.x, dy = ev.y - xv.y, dz = ev.z - xv.z, dw = ev.w - xv.w;
        float4 q = make_float4(xv.x + dx, xv.y + dy, xv.z + dz, xv.w + dw);
        *reinterpret_cast<float4*>(qout + (size_t)grow * DDIM + lane * 4) = q;
        float s = dx * dx + dy * dy + dz * dz + dw * dw;
#pragma unroll
        for (int m = 32; m >= 1; m >>= 1) s += __shfl_xor(s, m, 64);
        ssum += s;
    }
    if (lane == 0) lred[w] = ssum;
    __syncthreads();
    if (threadIdx.x == 0)
        loss_part[blockIdx.x] = (lred[0] + lred[1]) + (lred[2] + lred[3]);
}

// ---------------- scalars: vq_loss (reduce partials), perplexity ---------------
__global__ __launch_bounds__(1024) void scalar_kernel(
    const u32* __restrict__ hist, const float* __restrict__ loss_part,
    float* __restrict__ out_loss, float* __restrict__ out_perp) {
    __shared__ double lred[16];
    __shared__ float ered[16];
    int t = threadIdx.x;
    double ls = 0.0;
#pragma unroll
    for (int i = 0; i < RG_BLOCKS / 1024; ++i)
        ls += (double)loss_part[t + i * 1024];
    float p = (float)hist[t] / 65536.0f;
    float es = p * logf(p + 1e-10f);
#pragma unroll
    for (int m = 32; m >= 1; m >>= 1) {
        ls += __shfl_xor(ls, m, 64);
        es += __shfl_xor(es, m, 64);
    }
    if ((t & 63) == 0) { lred[t >> 6] = ls; ered[t >> 6] = es; }
    __syncthreads();
    if (t < 64) {
        double lv = (t < 16) ? lred[t] : 0.0;
        float ev = (t < 16) ? ered[t] : 0.0f;
#pragma unroll
        for (int m = 32; m >= 1; m >>= 1) {
            lv += __shfl_xor(lv, m, 64);
            ev += __shfl_xor(ev, m, 64);
        }
        if (t == 0) {
            *out_perp = expf(-ev);
            double ml = lv / (double)((size_t)NROWS * DDIM);
            *out_loss = (float)(ml * 0.25 + ml);  // beta*commit + delta*embed (equal)
        }
    }
}

extern "C" void kernel_launch(void* const* d_in, const int* in_sizes, int n_in,
                              void* d_out, int out_size, void* d_ws, size_t ws_size,
                              hipStream_t stream) {
    const float* lat = (const float*)d_in[0];
    const float* emb = (const float*)d_in[1];
    float* out = (float*)d_out;
    char* ws = (char*)d_ws;

    u32* cand_cnt = (u32*)ws;                          // 262144 B
    u16* cand = (u16*)(ws + 262144);                   // 2097152 B
    float* cand_dv = (float*)(ws + 2359296);           // 4194304 B
    float* row_sq = (float*)(ws + 6553600);            // 262144 B
    float* emb_sq = (float*)(ws + 6815744);            // 4096 B
    u32* hist = (u32*)(ws + 6819840);                  // 4096 B
    float* loss_part = (float*)(ws + 6823936);         // 16384 B
    u16* Apre = (u16*)(ws + 6840320);                  // 33554432 B
    u16* Bpre = (u16*)(ws + 40394752);                 // 524288 B

    convert_kernel<<<(NROWS * 32 + KCODES * 32) / 256, 256, 0, stream>>>(
        lat, emb, Apre, Bpre, row_sq, emb_sq, cand_cnt, hist);
    dist_row_kernel<<<4096, 256, 0, stream>>>(Apre, Bpre, row_sq, emb_sq,
                                              out + DIST_OFF, cand_cnt, cand, cand_dv);
    refine_gather_kernel<<<RG_BLOCKS, 256, 0, stream>>>(lat, emb, row_sq, emb_sq,
                                                        cand_cnt, cand, cand_dv,
                                                        out + Q_OFF, out + IND_OFF,
                                                        hist, loss_part);
    scalar_kernel<<<1, 1024, 0, stream>>>(hist, loss_part,
                                          out + LOSS_OFF, out + PERP_OFF);
}